// Round 9
// baseline (241.821 us; speedup 1.0000x reference)
//
#include <hip/hip_runtime.h>
#include <stdint.h>

typedef _Float16 f16;
typedef _Float16 f16x4 __attribute__((ext_vector_type(4)));
typedef _Float16 f16x8 __attribute__((ext_vector_type(8)));
typedef float f32x4 __attribute__((ext_vector_type(4)));

#define K_DIM 1600
#define NF_DIM 6400
#define KPAD 1664   // 26 tiles of 64
#define NKT 26
#define KPB (KPAD * 2)  // row stride bytes = 3328

// GEMM geometry: BM=256, BN=320, BK=64 -> 32x20 = 640 tiles (2.5/CU).
// 8 waves (2m x 4n), wave tile 128x80 -> per-FLOP LDS traffic cut 1.48x vs 64x80.
#define ABYTES 32768
#define BBYTES 40960
#define BUFSZ (ABYTES + BBYTES)  // 73728
#define BOFF ABYTES

// ---------- async global->LDS 16B copy ----------
__device__ __forceinline__ void async_copy16(const void* g, void* l) {
    __builtin_amdgcn_global_load_lds(
        (const __attribute__((address_space(1))) void*)(uintptr_t)g,
        (__attribute__((address_space(3))) void*)(uint32_t)(uintptr_t)l,
        16, 0, 0);
}

// ---------- block-wide max (256 threads = 4 waves) ----------
__device__ __forceinline__ float blockMax(float v, float* sm) {
#pragma unroll
    for (int off = 32; off > 0; off >>= 1)
        v = fmaxf(v, __shfl_down(v, off, 64));
    int wid = threadIdx.x >> 6, lane = threadIdx.x & 63;
    if (lane == 0) sm[wid] = v;
    __syncthreads();
    if (threadIdx.x == 0) {
        float m = sm[0];
        for (int i = 1; i < (int)(blockDim.x >> 6); ++i) m = fmaxf(m, sm[i]);
        sm[0] = m;
    }
    __syncthreads();
    return sm[0];
}

// ---------- per-token activation quant ----------
__global__ void quant_x_kernel(const float* __restrict__ x, f16* __restrict__ qx,
                               float* __restrict__ ax) {
    __shared__ float sm[4];
    size_t row = blockIdx.x;
    const float* xr = x + row * (size_t)K_DIM;
    float m = 0.f;
    const int n4 = K_DIM >> 2;
    for (int i = threadIdx.x; i < n4; i += blockDim.x) {
        float4 v = ((const float4*)xr)[i];
        m = fmaxf(fmaxf(fmaxf(fabsf(v.x), fabsf(v.y)), fmaxf(fabsf(v.z), fabsf(v.w))), m);
    }
    m = blockMax(m, sm);
    float s = 127.0f / (m + 1e-6f);
    if (threadIdx.x == 0) ax[row] = 1.0f / (s + 1e-6f);
    f16* qr = qx + row * (size_t)KPAD;
    for (int i = threadIdx.x; i < n4; i += blockDim.x) {
        float4 v = ((const float4*)xr)[i];
        f16x4 q;
        q[0] = (f16)rintf(v.x * s);
        q[1] = (f16)rintf(v.y * s);
        q[2] = (f16)rintf(v.z * s);
        q[3] = (f16)rintf(v.w * s);
        *(f16x4*)&qr[i * 4] = q;
    }
    if (threadIdx.x < 16) {
        f16x4 z = {};
        *(f16x4*)&qr[K_DIM + threadIdx.x * 4] = z;
    }
}

// ---------- per-row weight scale ----------
__global__ void wscale_kernel(const float* __restrict__ w, float* __restrict__ sw) {
    __shared__ float sm[4];
    size_t k = blockIdx.x;
    const float* wr = w + k * (size_t)NF_DIM;
    float m = 0.f;
    const int n4 = NF_DIM >> 2;
    for (int i = threadIdx.x; i < n4; i += blockDim.x) {
        float4 v = ((const float4*)wr)[i];
        m = fmaxf(fmaxf(fmaxf(fabsf(v.x), fabsf(v.y)), fmaxf(fabsf(v.z), fabsf(v.w))), m);
    }
    m = blockMax(m, sm);
    if (threadIdx.x == 0) sw[k] = 127.0f / (m + 1e-6f);
}

// ---------- quantize + transpose weight -> wqt[N][KPAD] fp16 ----------
__global__ void wtq_kernel(const float* __restrict__ w, const float* __restrict__ sw,
                           f16* __restrict__ wqt) {
    __shared__ f16 t[64][80];
    int k0 = blockIdx.x * 64;
    int f0 = blockIdx.y * 64;
    int tid = threadIdx.x;
    if (k0 >= K_DIM) {
        int fr = tid >> 2;
        int ch = (tid & 3) << 4;
        float4 z = {};
        float4* dst = (float4*)&wqt[(size_t)(f0 + fr) * KPAD + k0 + ch];
        dst[0] = z;
        dst[1] = z;
        return;
    }
    int rr = tid >> 4;
    int cc = (tid & 15) << 2;
#pragma unroll
    for (int i = 0; i < 4; ++i) {
        int r = rr + i * 16;
        float s = sw[k0 + r];
        float inv = 1.0f / (s + 1e-6f);
        float4 v = *(const float4*)&w[(size_t)(k0 + r) * NF_DIM + f0 + cc];
        t[cc + 0][r] = (f16)(rintf(v.x * s) * inv);
        t[cc + 1][r] = (f16)(rintf(v.y * s) * inv);
        t[cc + 2][r] = (f16)(rintf(v.z * s) * inv);
        t[cc + 3][r] = (f16)(rintf(v.w * s) * inv);
    }
    __syncthreads();
    int fr = tid >> 2;
    int ch = (tid & 3) << 4;
    const float4* src = (const float4*)&t[fr][ch];
    float4* dst = (float4*)&wqt[(size_t)(f0 + fr) * KPAD + k0 + ch];
    dst[0] = src[0];
    dst[1] = src[1];
}

// ---------- 256x320 GEMM: 8 phases/K-step, 1 barrier + 1 vmcnt(0)/K-step ----------
__global__ __launch_bounds__(512, 1) void gemm256x320(
    const f16* __restrict__ A,    // [M][KPAD]
    const f16* __restrict__ Bt,   // [N][KPAD]
    const float* __restrict__ ax,
    const float* __restrict__ bias,
    float* __restrict__ C, int M, int N) {
    extern __shared__ char lds[];
    // buf b at lds + b*BUFSZ: A[256][64]f16 @+0, B[320][64]f16 @+32768

    const int tid = threadIdx.x;
    const int lane = tid & 63;
    const int wv = tid >> 6;   // 0..7
    const int wm = wv >> 2;    // 0..1 (128-row half)
    const int wn = wv & 3;     // 0..3 (80-col quarter)
    const int lr = lane & 15;
    const int lg = lane >> 4;

    const int bid = blockIdx.x;
    const int cpx = gridDim.x >> 3;     // 80 (640 % 8 == 0 -> bijective)
    const int swz = (bid & 7) * cpx + (bid >> 3);
    const int tm = swz & 31;            // tn-major: consecutive swz share B panel
    const int tn = swz >> 5;
    const size_t m0 = (size_t)tm * 256, n0 = (size_t)tn * 320;

    // ---- staging pointers (inverse-swizzled source, linear LDS dest) ----
    const int srow8 = lane >> 3;
    const int sslot = (lane & 7) ^ srow8;
    const char* pA = (const char*)A + (m0 + (size_t)(wv * 32 + srow8)) * KPB + sslot * 16;
    const char* pB = (const char*)Bt + (n0 + (size_t)(wv * 40 + srow8)) * KPB + sslot * 16;
    const int LA0 = wv * 4096 + lane * 16;          // A dest base (j at +1024)
    const int LB0 = BOFF + wv * 5120 + lane * 16;   // B dest base (c at +1024)

    // A tile 256x64: 4 loads/thread; B tile 320x64: 5 loads/thread
#define ST_A(bufo, t)                                                          \
    {                                                                          \
        const char* g_ = pA + (size_t)(t) * 128;                               \
        _Pragma("unroll") for (int j_ = 0; j_ < 4; ++j_)                       \
            async_copy16(g_ + (size_t)(j_ * 8) * KPB,                          \
                         lds + (bufo) + LA0 + j_ * 1024);                      \
    }
#define ST_B(bufo, t)                                                          \
    {                                                                          \
        const char* g_ = pB + (size_t)(t) * 128;                               \
        _Pragma("unroll") for (int c_ = 0; c_ < 5; ++c_)                       \
            async_copy16(g_ + (size_t)(c_ * 8) * KPB,                          \
                         lds + (bufo) + LB0 + c_ * 1024);                      \
    }

    // ---- fragment-read offsets (XOR swizzle folded per-thread) ----
    const int adr0 = (wm * 128 + lr) * 128 + ((((lg)) ^ (lr & 7)) << 4);      // A kk=0
    const int adr1 = (wm * 128 + lr) * 128 + (((4 + lg) ^ (lr & 7)) << 4);    // A kk=1
    const int bdr0 = BOFF + (wn * 80 + lr) * 128 + (((lg) ^ (lr & 7)) << 4);
    const int bdr1 = BOFF + (wn * 80 + lr) * 128 + (((4 + lg) ^ (lr & 7)) << 4);

    // A piece p (0..3) = m-frags 2p,2p+1 (rows wm*128 + p*32 .. +31)
#define RD_P(dst, bufo, p, AOFF)                                       \
    {                                                                  \
        const char* p_ = lds + (bufo) + (AOFF) + (p) * 4096;           \
        dst[0] = *(const f16x8*)(p_);                                  \
        dst[1] = *(const f16x8*)(p_ + 2048);                           \
    }
#define RD_B5(dst, bufo, BOFFK)                                        \
    {                                                                  \
        const char* p_ = lds + (bufo) + (BOFFK);                       \
        _Pragma("unroll") for (int n_ = 0; n_ < 5; ++n_)               \
            dst[n_] = *(const f16x8*)(p_ + n_ * 2048);                 \
    }
#define RD_B01(dst, bufo, BOFFK)                                       \
    {                                                                  \
        const char* p_ = lds + (bufo) + (BOFFK);                       \
        dst[0] = *(const f16x8*)(p_);                                  \
        dst[1] = *(const f16x8*)(p_ + 2048);                           \
    }
#define RD_B234(dst, bufo, BOFFK)                                      \
    {                                                                  \
        const char* p_ = lds + (bufo) + (BOFFK);                       \
        dst[2] = *(const f16x8*)(p_ + 2 * 2048);                       \
        dst[3] = *(const f16x8*)(p_ + 3 * 2048);                       \
        dst[4] = *(const f16x8*)(p_ + 4 * 2048);                       \
    }

#define BARRIER __builtin_amdgcn_s_barrier()
#define LGKM(n) asm volatile("s_waitcnt lgkmcnt(" #n ")" ::: "memory")
#define VM0 asm volatile("s_waitcnt vmcnt(0)" ::: "memory")
#define SB0 __builtin_amdgcn_sched_barrier(0)

    // 10 MFMA: A piece (2 frags -> acc rows R0,R0+1) x 5 B frags
#define MF10(AF, BF, R0)                                                          \
    {                                                                             \
        __builtin_amdgcn_s_setprio(1);                                            \
        _Pragma("unroll") for (int a_ = 0; a_ < 2; ++a_)                          \
        _Pragma("unroll") for (int n_ = 0; n_ < 5; ++n_)                          \
            acc[(R0) + a_][n_] = __builtin_amdgcn_mfma_f32_16x16x32_f16(          \
                AF[a_], BF[n_], acc[(R0) + a_][n_], 0, 0, 0);                     \
        __builtin_amdgcn_s_setprio(0);                                            \
    }

    // One K-step. ds FIFO ledger (per wave), entering with 7 (aP piece0-k0 + Bk0):
    //  ph1 +4 w(4) | ph2 +5 w(7) | ph3 +2 w(5) | ph4 +2 w(2) | ph5 +2 w(2)
    //  ph6 +2 w(2) | ph7 +2 w(2) | ph8 w(0) then +7 (next tile) -> invariant 7.
    // vm: ph1 +4 (A,t+1), ph3 +5 (B,t+1), ph8 VM0 (issue distance 5-7 phases).
    // Single barrier (ph8, after VM0+LGKM(0)): all CUR reads retired before it,
    // so next tile's staging into CUR cannot race stragglers.
#define TILE(CUR, NXT, tn1)                                           \
    {                                                                 \
        /* ph1 */                                                     \
        RD_P(aN, CUR, 1, adr0);                                       \
        RD_B01(Bk1, CUR, bdr1);                                       \
        ST_A(NXT, tn1);                                               \
        LGKM(4); SB0;                                                 \
        MF10(aP, Bk0, 0);                                             \
        /* ph2 */                                                     \
        RD_P(aP, CUR, 2, adr0);                                       \
        RD_B234(Bk1, CUR, bdr1);                                      \
        LGKM(7); SB0;                                                 \
        MF10(aN, Bk0, 2);                                             \
        /* ph3 */                                                     \
        RD_P(aN, CUR, 3, adr0);                                       \
        ST_B(NXT, tn1);                                               \
        LGKM(5); SB0;                                                 \
        MF10(aP, Bk0, 4);                                             \
        /* ph4 */                                                     \
        RD_P(aP, CUR, 0, adr1);                                       \
        LGKM(2); SB0;                                                 \
        MF10(aN, Bk0, 6);                                             \
        /* ph5 */                                                     \
        RD_P(aN, CUR, 1, adr1);                                       \
        LGKM(2); SB0;                                                 \
        MF10(aP, Bk1, 0);                                             \
        /* ph6 */                                                     \
        RD_P(aP, CUR, 2, adr1);                                       \
        LGKM(2); SB0;                                                 \
        MF10(aN, Bk1, 2);                                             \
        /* ph7 */                                                     \
        RD_P(aN, CUR, 3, adr1);                                       \
        LGKM(2); SB0;                                                 \
        MF10(aP, Bk1, 4);                                             \
        /* ph8 */                                                     \
        VM0; LGKM(0); SB0;                                            \
        BARRIER;                                                      \
        RD_P(aP, NXT, 0, adr0);                                       \
        RD_B5(Bk0, NXT, bdr0);                                        \
        SB0;                                                          \
        MF10(aN, Bk1, 6);                                             \
    }

    f32x4 acc[8][5] = {};
    f16x8 aP[2], aN[2], Bk0[5], Bk1[5];

    // ---- prologue: stage tile0 -> buf0; pre-read ph1 operands ----
    ST_A(0, 0);
    ST_B(0, 0);
    VM0;
    BARRIER;
    RD_P(aP, 0, 0, adr0);
    RD_B5(Bk0, 0, bdr0);   // 7 ds outstanding

    for (int i = 0; i < NKT / 2; ++i) {
        const int ta = 2 * i + 1;                                // staged during even tile
        const int tb = (2 * i + 2 < NKT) ? 2 * i + 2 : NKT - 1;  // clamped (dead on last)
        TILE(0, BUFSZ, ta);
        TILE(BUFSZ, 0, tb);
    }
    asm volatile("s_waitcnt vmcnt(0) lgkmcnt(0)" ::: "memory");

    // ---- epilogue: direct stores, ax*acc + bias ----
    float bv[5];
#pragma unroll
    for (int n_ = 0; n_ < 5; ++n_) bv[n_] = bias[n0 + wn * 80 + n_ * 16 + lr];
#pragma unroll
    for (int a = 0; a < 8; ++a) {
#pragma unroll
        for (int j = 0; j < 4; ++j) {
            size_t row = m0 + wm * 128 + a * 16 + lg * 4 + j;
            float axv = ax[row];
            float* crow = C + row * (size_t)N + n0 + wn * 80;
#pragma unroll
            for (int n_ = 0; n_ < 5; ++n_)
                crow[n_ * 16 + lr] = acc[a][n_][j] * axv + bv[n_];
        }
    }
}

extern "C" void kernel_launch(void* const* d_in, const int* in_sizes, int n_in,
                              void* d_out, int out_size, void* d_ws, size_t ws_size,
                              hipStream_t stream) {
    const float* x = (const float*)d_in[0];
    const float* w = (const float*)d_in[1];
    const float* bias = (const float*)d_in[2];
    float* out = (float*)d_out;

    const int M = in_sizes[0] / K_DIM;  // 8192
    const int N = NF_DIM;               // 6400

    char* ws = (char*)d_ws;
    f16* qx = (f16*)ws;
    f16* wqt = (f16*)(ws + (size_t)M * KPAD * 2);
    float* ax = (float*)(ws + (size_t)M * KPAD * 2 + (size_t)N * KPAD * 2);
    float* sw = ax + M;

    quant_x_kernel<<<M, 256, 0, stream>>>(x, qx, ax);
    wscale_kernel<<<K_DIM, 256, 0, stream>>>(w, sw);
    wtq_kernel<<<dim3(KPAD / 64, NF_DIM / 64), 256, 0, stream>>>(w, sw, wqt);

    (void)hipFuncSetAttribute((const void*)gemm256x320,
                              hipFuncAttributeMaxDynamicSharedMemorySize, 2 * BUFSZ);
    gemm256x320<<<(M / 256) * (N / 320), 512, 2 * BUFSZ, stream>>>(qx, wqt, ax, bias, out, M, N);
}